// Round 11
// baseline (675.929 us; speedup 1.0000x reference)
//
#include <hip/hip_runtime.h>

typedef __attribute__((ext_vector_type(8))) short bf16x8;
typedef __attribute__((ext_vector_type(4))) float f32x4;

#define N_NODES   100000
#define NPERM_    100000
#define L_        16
#define G_        1024
#define CAP_      20
#define OVF_MAX   4096

__device__ inline unsigned short f32_to_bf16(float f) {
    unsigned u = __float_as_uint(f);
    unsigned r = (u + 0x7fff + ((u >> 16) & 1)) >> 16;   // RNE
    return (unsigned short)r;
}
__device__ inline float bflo(unsigned u) { return __uint_as_float(u << 16); }
__device__ inline float bfhi(unsigned u) { return __uint_as_float(u & 0xffff0000u); }
__device__ inline float bfup(unsigned short s) { return __uint_as_float((unsigned)s << 16); }
__device__ inline unsigned pk2(float a, float b) {
    return (unsigned)f32_to_bf16(a) | ((unsigned)f32_to_bf16(b) << 16);
}

// global_load_lds: 16B per lane, LDS dest = base + lane*16 (wave-uniform base)
typedef __attribute__((address_space(1))) const unsigned int gas_u32;
typedef __attribute__((address_space(3))) unsigned int las_u32;
__device__ __forceinline__ void gld16(const void* g, void* l) {
    __builtin_amdgcn_global_load_lds((gas_u32*)g, (las_u32*)l, 16, 0, 0);
}

// ---------------------------------------------------------------------------
// W_lrp [4][64 k][64 c][16 l] -> split bf16, MFMA-fragment-ordered:
// Wt2[layer][ho][l][sc=s*4+cb][lane][j]  (lane-linear 16B chunks; ho=0 hi, 1 lo)
// content = W[k = s*32+(lane>>4)*8+j][c = cb*16+(lane&15)] at l.
__global__ __launch_bounds__(256) void k_prep_w(const float* __restrict__ W,
                                                unsigned short* __restrict__ Wt2) {
    int o = blockIdx.x * 256 + threadIdx.x;   // 524288
    int j    = o & 7;
    int lane = (o >> 3) & 63;
    int sc   = (o >> 9) & 7;
    int l    = (o >> 12) & 15;
    int ho   = (o >> 16) & 1;
    int i    = o >> 17;
    int s = sc >> 2, cb = sc & 3;
    int k = s * 32 + (lane >> 4) * 8 + j;
    int c = cb * 16 + (lane & 15);
    float f = W[(((i * 64 + k) * 64) + c) * 16 + l];
    unsigned short hh = f32_to_bf16(f);
    Wt2[o] = ho ? f32_to_bf16(f - bfup(hh)) : hh;
}

// ---------------------------------------------------------------------------
// factor[n,c] = relu(degs[n]*A + B) @ W1 + b1 is piecewise-linear in degs[n].
__global__ __launch_bounds__(256) void k_prep_factor(const float* __restrict__ dn0_W,
                                                     const float* __restrict__ dn0_b,
                                                     const float* __restrict__ dn1_W,
                                                     const float* __restrict__ dn1_b,
                                                     float* __restrict__ tab,   // [4][129][64][2]
                                                     float* __restrict__ thr) { // [4][128]
    int i     = blockIdx.x;
    int chunk = blockIdx.y;
    int tid   = threadIdx.x;
    __shared__ float A[128], B[128], ts[128], tv[128];
    __shared__ float W1l[128 * 64];
    if (tid < 128) { A[tid] = dn0_W[i * 128 + tid]; B[tid] = dn0_b[i * 128 + tid]; }
    {
        const float4* src = (const float4*)(dn1_W + (size_t)i * 8192);
        float4*       dst = (float4*)W1l;
        for (int t = tid; t < 2048; t += 256) dst[t] = src[t];
    }
    __syncthreads();
    if (tid < 128) {
        float a = A[tid], b = B[tid];
        float tj = -b / a;
        if (a == 0.f || !(tj > 0.f)) tj = 1e30f;
        tv[tid] = tj;
    }
    __syncthreads();
    if (tid < 128) {
        float tj = tv[tid];
        int rank = 0;
        for (int j = 0; j < 128; ++j) {
            float o = tv[j];
            rank += (o < tj) || (o == tj && j < tid);
        }
        ts[rank] = tj;
    }
    __syncthreads();
    if (chunk == 0 && tid < 128) thr[i * 128 + tid] = ts[tid];
    int s0 = chunk * 17;
    int s1 = min(s0 + 17, 129);
    float* tb = tab + (size_t)i * 129 * 128;
    for (int item = s0 * 64 + tid; item < s1 * 64; item += 256) {
        int s = item >> 6;
        int c = item & 63;
        float lo = (s == 0) ? 0.f : ts[s - 1];
        float hi = (s == 128) ? 1e30f : ts[s];
        float g;
        if (lo > 1e29f)       g = 1e29f;
        else if (hi > 1e29f)  g = lo + 1.f;
        else                  g = 0.5f * (lo + hi);
        float alpha = 0.f, beta = dn1_b[i * 64 + c];
        for (int j = 0; j < 128; ++j) {
            if (fmaf(g, A[j], B[j]) > 0.f) {
                float w1 = W1l[j * 64 + c];
                alpha = fmaf(A[j], w1, alpha);
                beta  = fmaf(B[j], w1, beta);
            }
        }
        tb[s * 128 + c * 2 + 0] = alpha;
        tb[s * 128 + c * 2 + 1] = beta;
    }
}

// ---------------------------------------------------------------------------
__global__ __launch_bounds__(256) void k_atom(const float* __restrict__ feat,
                                              const float* __restrict__ W,
                                              const float* __restrict__ b,
                                              unsigned short* __restrict__ xb) {
    __shared__ float Wlds[28 * 64];
    __shared__ float blds[64];
    int tid = threadIdx.x;
    for (int t = tid; t < 28 * 64; t += 256) Wlds[t] = W[t];
    if (tid < 64) blds[tid] = b[tid];
    __syncthreads();
    int n = blockIdx.x * 4 + (tid >> 6);
    int c = tid & 63;
    if (n >= N_NODES) return;
    const float* fr = feat + n * 28;
    float acc = blds[c];
#pragma unroll
    for (int j = 0; j < 28; ++j) acc = fmaf(fr[j], Wlds[j * 64 + c], acc);
    xb[n * 64 + c] = f32_to_bf16(acc);
}

// ---------------------------------------------------------------------------
__global__ __launch_bounds__(256) void k_bucket(const int* __restrict__ prow,
                                                int* __restrict__ cntn,
                                                int* __restrict__ bucket,
                                                int* __restrict__ ovf,
                                                int* __restrict__ ovfc) {
    int d = blockIdx.x * 256 + threadIdx.x;
    if (d >= NPERM_) return;
    int n = prow[d];
    int s = atomicAdd(cntn + n, 1);
    if (s < CAP_) bucket[n * CAP_ + s] = d;
    else { int o = atomicAdd(ovfc, 1); if (o < OVF_MAX) ovf[o] = d; }
}

// ---------------------------------------------------------------------------
// MFMA gather-GEMM, v2: global_load_lds double-buffered staging, lane-linear
// (fragment-ordered) LDS layouts -> zero bank conflicts, no ds_writes in loop.
// Per phase: stage(l+1) -> buf^1; compute(l) from buf; __syncthreads (its
// vmcnt(0) drain lands AFTER a full phase of compute = latency hidden).
// Transform t = vn*x + ve*ef applied at A-frag read time.
__global__ __launch_bounds__(256, 3) void k_lrp(const unsigned short* __restrict__ xbuf,
                                                const int*   __restrict__ n2p_col,
                                                const float* __restrict__ n2p_val,
                                                const float* __restrict__ e2p_val,
                                                const float* __restrict__ edge_W,
                                                const float* __restrict__ edge_b,
                                                const unsigned short* __restrict__ Wt2, // [2][16][8][512] this layer
                                                const float* __restrict__ bl,
                                                unsigned short* __restrict__ hout) {
    __shared__ unsigned short Tb[2][4][2][512];   // [buf][wave][s][lane*8]   16 KB
    __shared__ unsigned short Wb[2][2][8][512];   // [buf][ho][s*4+cb][lane*8] 32 KB
    int tid = threadIdx.x;
    int lane = tid & 63;
    int w = tid >> 6;
    int r = lane & 15, q = lane >> 4;
    int d0 = blockIdx.x * 64;
    int myrow = w * 16 + r;
    int dg = min(d0 + myrow, NPERM_ - 1);
    size_t pbase = (size_t)dg * 16;

    // per-lane constant ef slice: k = s*32 + q*8 + j
    float efr[2][8];
#pragma unroll
    for (int s = 0; s < 2; ++s) {
        int kb = s * 32 + q * 8;
        float4 wa = *(const float4*)(edge_W + kb);
        float4 wc = *(const float4*)(edge_W + kb + 4);
        float4 ba = *(const float4*)(edge_b + kb);
        float4 bc = *(const float4*)(edge_b + kb + 4);
        efr[s][0] = wa.x + ba.x; efr[s][1] = wa.y + ba.y;
        efr[s][2] = wa.z + ba.z; efr[s][3] = wa.w + ba.w;
        efr[s][4] = wc.x + bc.x; efr[s][5] = wc.y + bc.y;
        efr[s][6] = wc.z + bc.z; efr[s][7] = wc.w + bc.w;
    }

    f32x4 acc[4];
#pragma unroll
    for (int cb = 0; cb < 4; ++cb) acc[cb] = (f32x4)0.f;

    auto stage = [&](int l, int buf, int col) {
        // A rows for this wave (per-lane source; dest lane-linear)
        const unsigned short* ap = xbuf + (size_t)col * 64 + q * 8;
        gld16(ap,      &Tb[buf][w][0][0]);
        gld16(ap + 32, &Tb[buf][w][1][0]);
        // W: this wave stages chunks w*4 .. w*4+3
        const unsigned short* wl = Wt2 + l * 4096;
#pragma unroll
        for (int i = 0; i < 4; ++i) {
            int c = w * 4 + i;
            gld16(wl + (c >> 3) * 65536 + (c & 7) * 512 + lane * 8,
                  &Wb[buf][c >> 3][c & 7][0]);
        }
    };

    int colA = n2p_col[pbase + 0];
    stage(0, 0, colA);
    colA = n2p_col[pbase + 1];
    float vnC = n2p_val[pbase + 0], veC = e2p_val[pbase + 0];
    __syncthreads();   // drains stage(0)

#pragma unroll 1
    for (int l = 0; l < L_; ++l) {
        int buf = l & 1;
        if (l < 15) stage(l + 1, buf ^ 1, colA);
        if (l < 14) colA = n2p_col[pbase + l + 2];
        float vn = vnC, ve = veC;
        if (l < 15) { vnC = n2p_val[pbase + l + 1]; veC = e2p_val[pbase + l + 1]; }
#pragma unroll
        for (int s = 0; s < 2; ++s) {
            uint4 v = *(const uint4*)&Tb[buf][w][s][lane * 8];
            uint4 aw;
            aw.x = pk2(fmaf(vn, bflo(v.x), ve * efr[s][0]),
                       fmaf(vn, bfhi(v.x), ve * efr[s][1]));
            aw.y = pk2(fmaf(vn, bflo(v.y), ve * efr[s][2]),
                       fmaf(vn, bfhi(v.y), ve * efr[s][3]));
            aw.z = pk2(fmaf(vn, bflo(v.z), ve * efr[s][4]),
                       fmaf(vn, bfhi(v.z), ve * efr[s][5]));
            aw.w = pk2(fmaf(vn, bflo(v.w), ve * efr[s][6]),
                       fmaf(vn, bfhi(v.w), ve * efr[s][7]));
            bf16x8 a0 = *(bf16x8*)&aw;
#pragma unroll
            for (int cb = 0; cb < 4; ++cb) {
                bf16x8 bh = *(const bf16x8*)&Wb[buf][0][s * 4 + cb][lane * 8];
                bf16x8 bo = *(const bf16x8*)&Wb[buf][1][s * 4 + cb][lane * 8];
                acc[cb] = __builtin_amdgcn_mfma_f32_16x16x32_bf16(a0, bh, acc[cb], 0, 0, 0);
                acc[cb] = __builtin_amdgcn_mfma_f32_16x16x32_bf16(a0, bo, acc[cb], 0, 0, 0);
            }
        }
        __syncthreads();
    }

    // epilogue: bias+relu -> bf16, LDS bounce (reuse Tb), clean 16B stores
    {
        unsigned short* F = &Tb[0][0][0][0] + w * 1024;   // 16x64 bf16 per wave
#pragma unroll
        for (int cb = 0; cb < 4; ++cb) {
            float bias = bl[cb * 16 + r];
#pragma unroll
            for (int reg = 0; reg < 4; ++reg)
                F[(q * 4 + reg) * 64 + cb * 16 + r] =
                    f32_to_bf16(fmaxf(acc[cb][reg] + bias, 0.f));
        }
#pragma unroll
        for (int ii = 0; ii < 2; ++ii) {
            int idx = lane + ii * 64;               // 16 rows x 8 uint4
            uint4 v = ((const uint4*)F)[idx];
            int R = d0 + w * 16 + (idx >> 3);
            if (R < NPERM_)
                *(uint4*)(hout + (size_t)R * 64 + (idx & 7) * 8) = v;
        }
    }
}

// ---------------------------------------------------------------------------
// x[n] = (bucket-gather pool of bf16 h) * (alpha[seg]*degs + beta[seg])
__global__ __launch_bounds__(256) void k_pool_seg(const unsigned short* __restrict__ h,
                                                  const int*   __restrict__ cntn,
                                                  const int*   __restrict__ bucket,
                                                  const int*   __restrict__ ovf,
                                                  const int*   __restrict__ ovfc,
                                                  const int*   __restrict__ prow,
                                                  const float* __restrict__ pval,
                                                  const float* __restrict__ degs,
                                                  const float* __restrict__ tab,  // [129][64][2]
                                                  const float* __restrict__ thr,  // [128]
                                                  float* __restrict__ x,
                                                  unsigned short* __restrict__ xbo,
                                                  int last) {
    __shared__ float thrl[128];
    int tid = threadIdx.x;
    if (tid < 128) thrl[tid] = thr[tid];
    __syncthreads();
    int n  = blockIdx.x * 16 + (tid >> 4);
    int c4 = (tid & 15) * 4;
    if (n >= N_NODES) return;
    float dgv = degs[n];
    int seg = 0;
    if (thrl[63]       < dgv) seg = 64;
    if (thrl[seg + 31] < dgv) seg += 32;
    if (thrl[seg + 15] < dgv) seg += 16;
    if (thrl[seg + 7]  < dgv) seg += 8;
    if (thrl[seg + 3]  < dgv) seg += 4;
    if (thrl[seg + 1]  < dgv) seg += 2;
    if (thrl[seg]      < dgv) seg += 1;
    float4 p = make_float4(0.f, 0.f, 0.f, 0.f);
    int cn = min(cntn[n], CAP_);
    for (int j = 0; j < cn; ++j) {
        int   d  = bucket[n * CAP_ + j];
        float pv = pval[d];
        ushort4 hv = *(const ushort4*)(h + (size_t)d * 64 + c4);
        p.x = fmaf(pv, bfup(hv.x), p.x);
        p.y = fmaf(pv, bfup(hv.y), p.y);
        p.z = fmaf(pv, bfup(hv.z), p.z);
        p.w = fmaf(pv, bfup(hv.w), p.w);
    }
    int novf = *ovfc;
    if (novf > 0) {
        int ne = novf < OVF_MAX ? novf : OVF_MAX;
        for (int e = 0; e < ne; ++e) {
            int d = ovf[e];
            if (prow[d] == n) {
                float pv = pval[d];
                ushort4 hv = *(const ushort4*)(h + (size_t)d * 64 + c4);
                p.x = fmaf(pv, bfup(hv.x), p.x);
                p.y = fmaf(pv, bfup(hv.y), p.y);
                p.z = fmaf(pv, bfup(hv.z), p.z);
                p.w = fmaf(pv, bfup(hv.w), p.w);
            }
        }
    }
    const float4* tf = (const float4*)(tab + (size_t)(seg * 64 + c4) * 2);
    float4 t0 = tf[0], t1 = tf[1];
    float4 xo;
    xo.x = p.x * fmaf(t0.x, dgv, t0.y);
    xo.y = p.y * fmaf(t0.z, dgv, t0.w);
    xo.z = p.z * fmaf(t1.x, dgv, t1.y);
    xo.w = p.w * fmaf(t1.z, dgv, t1.w);
    if (last) {
        *(float4*)(x + (size_t)n * 64 + c4) = xo;
    } else {
        ushort4 s;
        s.x = f32_to_bf16(xo.x); s.y = f32_to_bf16(xo.y);
        s.z = f32_to_bf16(xo.z); s.w = f32_to_bf16(xo.w);
        *(ushort4*)(xbo + (size_t)n * 64 + c4) = s;
    }
}

// ---------------------------------------------------------------------------
__global__ __launch_bounds__(256) void k_gpool(const float* __restrict__ x,
                                               const int* __restrict__ batch,
                                               float* __restrict__ out,
                                               float* __restrict__ cnt) {
    int wave = (blockIdx.x * 256 + threadIdx.x) >> 6;
    int lane = threadIdx.x & 63;
    int n0 = wave * 64;
    if (n0 >= N_NODES) return;
    int n1 = min(n0 + 64, N_NODES);
    int g = batch[n0];
    float s = 0.f, c = 0.f;
    for (int n = n0; n < n1; ++n) {
        int gn = batch[n];
        if (gn != g) {
            atomicAdd(out + (size_t)g * 64 + lane, s);
            if (lane == 0) atomicAdd(cnt + g, c);
            s = 0.f; c = 0.f; g = gn;
        }
        s += x[(size_t)n * 64 + lane];
        c += 1.f;
    }
    atomicAdd(out + (size_t)g * 64 + lane, s);
    if (lane == 0) atomicAdd(cnt + g, c);
}

__global__ __launch_bounds__(256) void k_gdiv(float* __restrict__ out,
                                              const float* __restrict__ cnt) {
    int idx = blockIdx.x * 256 + threadIdx.x;
    if (idx >= G_ * 64) return;
    out[idx] /= fmaxf(cnt[idx >> 6], 1.f);
}

// ---------------------------------------------------------------------------
extern "C" void kernel_launch(void* const* d_in, const int* in_sizes, int n_in,
                              void* d_out, int out_size, void* d_ws, size_t ws_size,
                              hipStream_t stream) {
    const float* node_feat = (const float*)d_in[0];
    const float* degs      = (const float*)d_in[1];
    const int*   batch     = (const int*)  d_in[2];
    const int*   n2p_col   = (const int*)  d_in[4];
    const float* n2p_val   = (const float*)d_in[5];
    const float* e2p_val   = (const float*)d_in[8];
    const int*   pool_row  = (const int*)  d_in[9];
    const float* pool_val  = (const float*)d_in[11];
    const float* atom_W    = (const float*)d_in[12];
    const float* atom_b    = (const float*)d_in[13];
    const float* edge_W    = (const float*)d_in[14];
    const float* edge_b    = (const float*)d_in[15];
    const float* W_lrp     = (const float*)d_in[16];
    const float* b_lrp     = (const float*)d_in[17];
    const float* dn0_W     = (const float*)d_in[18];
    const float* dn0_b     = (const float*)d_in[19];
    const float* dn1_W     = (const float*)d_in[20];
    const float* dn1_b     = (const float*)d_in[21];

    char* ws = (char*)d_ws;
    unsigned short* h      = (unsigned short*)(ws);                 // 12,800,000
    unsigned short* xb     = (unsigned short*)(ws + 12800000);      // 12,800,000
    unsigned short* Wt2    = (unsigned short*)(ws + 25600000);      //  1,048,576
    int*            bucket = (int*)           (ws + 26648576);      //  8,000,000
    int*            cntn   = (int*)           (ws + 34648576);      //    400,000
    int*            ovf    = (int*)           (ws + 35048576);      //     16,384
    int*            ovfc   = (int*)           (ws + 35064960);      //        128
    float*          tab    = (float*)         (ws + 35065088);      //    264,192
    float*          thr    = (float*)         (ws + 35329280);      //      2,048
    float*          cntg   = (float*)         (ws + 35331328);      //      4,096
    float*          x      = (float*)         (ws + 35335424);      // 25,600,000

    hipLaunchKernelGGL(k_prep_w, dim3(2048), dim3(256), 0, stream, W_lrp, Wt2);
    hipLaunchKernelGGL(k_prep_factor, dim3(4, 8), dim3(256), 0, stream,
                       dn0_W, dn0_b, dn1_W, dn1_b, tab, thr);
    hipLaunchKernelGGL(k_atom, dim3(25000), dim3(256), 0, stream,
                       node_feat, atom_W, atom_b, xb);
    hipMemsetAsync(cntn, 0, 416512, stream);   // cntn + ovf + ovfc in one shot
    hipLaunchKernelGGL(k_bucket, dim3(391), dim3(256), 0, stream,
                       pool_row, cntn, bucket, ovf, ovfc);
    for (int i = 0; i < 4; ++i) {
        hipLaunchKernelGGL(k_lrp, dim3(1563), dim3(256), 0, stream,
                           xb, n2p_col, n2p_val, e2p_val, edge_W, edge_b,
                           Wt2 + (size_t)i * 131072, b_lrp + i * 64, h);
        hipLaunchKernelGGL(k_pool_seg, dim3(6250), dim3(256), 0, stream,
                           h, cntn, bucket, ovf, ovfc, pool_row, pool_val,
                           degs, tab + (size_t)i * 129 * 128, thr + i * 128,
                           x, xb, (i == 3) ? 1 : 0);
    }
    hipMemsetAsync(d_out, 0, (size_t)G_ * 64 * 4, stream);
    hipMemsetAsync(cntg, 0, G_ * 4, stream);
    hipLaunchKernelGGL(k_gpool, dim3(391), dim3(256), 0, stream,
                       x, batch, (float*)d_out, cntg);
    hipLaunchKernelGGL(k_gdiv, dim3(256), dim3(256), 0, stream,
                       (float*)d_out, cntg);
}